// Round 15
// baseline (71.801 us; speedup 1.0000x reference)
//
#include <hip/hip_runtime.h>
#include <hip/hip_bf16.h>

#define N_ROWS 32768
#define K_DIM 512
#define OUT_DIM 512
#define N_TYPES 8
#define BM 128
#define BN 256
#define BK 64
#define TPB 256             // row-tiles per type (fixed segment: 256*128 = N)

typedef __attribute__((ext_vector_type(8))) short bf16x8;
typedef __attribute__((ext_vector_type(4))) float f32x4;

__device__ inline ushort f2bf(float f) {
    __hip_bfloat16 h = __float2bfloat16(f);
    return *reinterpret_cast<ushort*>(&h);
}

__device__ inline void gload_lds16(const void* g, void* l) {
    __builtin_amdgcn_global_load_lds(
        (const __attribute__((address_space(1))) void*)g,
        (__attribute__((address_space(3))) void*)l, 16, 0, 0);
}

// meta[0..7] = per-type cursors; final value after k_fill = per-type count.
// row_ids: fixed 1-MB layout, segment t at [t*N_ROWS, ...), rest stays -1.
__global__ void k_fill(const int* __restrict__ x_type, int* meta, int* __restrict__ row_ids) {
    __shared__ int lcnt[N_TYPES];
    __shared__ int lbase[N_TYPES];
    if (threadIdx.x < N_TYPES) lcnt[threadIdx.x] = 0;
    __syncthreads();
    int i = blockIdx.x * 256 + threadIdx.x;
    int t = x_type[i];
    int lpos = atomicAdd(&lcnt[t], 1);
    __syncthreads();
    if (threadIdx.x < N_TYPES)
        lbase[threadIdx.x] = (lcnt[threadIdx.x] > 0)
            ? atomicAdd(&meta[threadIdx.x], lcnt[threadIdx.x]) : 0;
    __syncthreads();
    row_ids[(size_t)t * N_ROWS + lbase[t] + lpos] = i;
}

// W[t][k][c] fp32 -> Wt[t][c][k] bf16   (64x64 tiles through LDS)
__global__ void k_wt(const float* __restrict__ W, ushort* __restrict__ Wt) {
    __shared__ float tile[64][65];
    int t = blockIdx.x, kb = blockIdx.y, cb = blockIdx.z;
    const float* src = W + (size_t)t * K_DIM * OUT_DIM + (size_t)kb * 64 * OUT_DIM + cb * 64;
    #pragma unroll
    for (int j = 0; j < 16; ++j) {
        int idx = threadIdx.x + j * 256;
        int r = idx >> 6, c = idx & 63;
        tile[r][c] = src[(size_t)r * OUT_DIM + c];
    }
    __syncthreads();
    ushort* dst = Wt + (size_t)t * OUT_DIM * K_DIM + (size_t)(cb * 64) * K_DIM + kb * 64;
    #pragma unroll
    for (int j = 0; j < 16; ++j) {
        int idx = threadIdx.x + j * 256;
        int cc = idx >> 6, kk = idx & 63;
        dst[(size_t)cc * K_DIM + kk] = f2bf(tile[kk][cc]);
    }
}

// 128x256 tile, 512 thr, 8 waves (each 64x64 out, acc[4][4] = r3's proven
// compute core, VGPR ~96), BK=64 single-buffered, LDS 48.7 KB.
// 32 MFMA + 16 ds_read_b128 per wave per barrier-pair (2x r14's ratio).
// Involution swizzle (0 conflicts proven): granule g ^= (id&7) in 128-B rows;
// B via global_load_lds, involution folded into per-lane SOURCE (rule #21);
// A reg-staged fp32->bf16 (16 elems/thread) with swizzled ds_write.
__global__ __launch_bounds__(512, 4) void k_gemm14(
    const float* __restrict__ x, const ushort* __restrict__ Wt,
    const int* __restrict__ meta, const int* __restrict__ row_ids,
    float* __restrict__ out) {

    __shared__ ushort As[BM * BK];   // 16384 B, [row][64k], 128 B/row
    __shared__ ushort Bs[BN * BK];   // 32768 B, [col][64k], 128 B/col-row
    __shared__ int rids[BM];

    int b = blockIdx.x;              // 0..2047; row-tiles fastest
    int type = b >> 8;
    int r0 = (b & (TPB - 1)) * BM;
    if (r0 >= meta[type]) return;    // empty tile

    int tid = threadIdx.x;
    int wave = tid >> 6, lane = tid & 63;

    if (tid < BM) rids[tid] = row_ids[(size_t)type * N_ROWS + r0 + tid];
    __syncthreads();

    int c0 = blockIdx.y * BN;
    const ushort* Wtt = Wt + (size_t)type * OUT_DIM * K_DIM + (size_t)c0 * K_DIM;

    // ---- A staging role: 4 threads/row, 16 elems (2 granules) each ----
    int sa_row  = tid >> 2;
    int sa_slot = tid & 3;           // 16-elem quarter of the 64-k row
    int sa_rid  = rids[sa_row];
    const float* sa_src = x + (size_t)max(sa_rid, 0) * K_DIM + sa_slot * 16;

    // ---- B staging role: chunk = 8 cols x 128 B (1 KB); lane -> (col,pos);
    //      source granule = pos ^ (col&7)  (involution on SOURCE) ----
    int sb_colgrp = lane >> 3;                               // 0..7
    int sb_koff   = (((lane & 7) * 16) ^ (sb_colgrp << 4)) >> 1;  // elems

    int wrb = (wave >> 2) * 64;      // wave row base (0/64)
    int wcb = (wave & 3) * 64;       // wave col base (0..192)
    int lrow = lane & 15;
    int lkb16 = (lane >> 4) * 16;    // 16-B k-fragment offset

    f32x4 acc[4][4] = {};

    #pragma unroll 1
    for (int kk = 0; kk < K_DIM; kk += BK) {
        // ---- stage B: 4 chunks/wave, 32 chunks = 256 cols ----
        #pragma unroll
        for (int j = 0; j < 4; ++j) {
            int chunk = wave * 4 + j;
            int col = chunk * 8 + sb_colgrp;
            gload_lds16(Wtt + (size_t)col * K_DIM + kk + sb_koff,
                        (char*)Bs + chunk * 1024);
        }
        // ---- stage A: 16 fp32 -> 16 bf16, 2 swizzled ds_write_b128 ----
        {
            float4 v[4];
            #pragma unroll
            for (int q = 0; q < 4; ++q)
                v[q] = (sa_rid >= 0)
                    ? *reinterpret_cast<const float4*>(sa_src + kk + q * 4)
                    : float4{0.f, 0.f, 0.f, 0.f};
            #pragma unroll
            for (int q = 0; q < 2; ++q) {
                ushort tmp[8] = {
                    f2bf(v[q*2].x),   f2bf(v[q*2].y),   f2bf(v[q*2].z),   f2bf(v[q*2].w),
                    f2bf(v[q*2+1].x), f2bf(v[q*2+1].y), f2bf(v[q*2+1].z), f2bf(v[q*2+1].w) };
                int p = sa_slot * 2 + q;
                int byte = (sa_row * 128 + p * 16) ^ ((sa_row & 7) << 4);
                *reinterpret_cast<uint4*>((char*)As + byte) =
                    *reinterpret_cast<const uint4*>(tmp);
            }
        }
        __syncthreads();

        // ---- compute: 2 k-halves x 16 MFMA (32 MFMA, 16 ds_read_b128) ----
        #pragma unroll
        for (int s = 0; s < 2; ++s) {
            bf16x8 af[4], bfr[4];
            #pragma unroll
            for (int mi = 0; mi < 4; ++mi) {
                int row = wrb + mi * 16 + lrow;
                int byte = (row * 128 + s * 64 + lkb16) ^ ((row & 7) << 4);
                af[mi] = *reinterpret_cast<const bf16x8*>((const char*)As + byte);
            }
            #pragma unroll
            for (int ni = 0; ni < 4; ++ni) {
                int col = wcb + ni * 16 + lrow;
                int byte = (col * 128 + s * 64 + lkb16) ^ ((col & 7) << 4);
                bfr[ni] = *reinterpret_cast<const bf16x8*>((const char*)Bs + byte);
            }
            #pragma unroll
            for (int mi = 0; mi < 4; ++mi)
                #pragma unroll
                for (int ni = 0; ni < 4; ++ni)
                    acc[mi][ni] = __builtin_amdgcn_mfma_f32_16x16x32_bf16(
                        af[mi], bfr[ni], acc[mi][ni], 0, 0, 0);
        }
        __syncthreads();
    }

    // epilogue: D row = (lane>>4)*4 + rr, col = lane&15
    int rgrp = (lane >> 4) * 4;
    #pragma unroll
    for (int mi = 0; mi < 4; ++mi) {
        #pragma unroll
        for (int rr = 0; rr < 4; ++rr) {
            int lr = wrb + mi * 16 + rgrp + rr;
            int gr = rids[lr];
            if (gr >= 0) {
                float* dst = out + (size_t)gr * OUT_DIM + c0 + wcb;
                #pragma unroll
                for (int ni = 0; ni < 4; ++ni)
                    dst[ni * 16 + lrow] = acc[mi][ni][rr];
            }
        }
    }
}

extern "C" void kernel_launch(void* const* d_in, const int* in_sizes, int n_in,
                              void* d_out, int out_size, void* d_ws, size_t ws_size,
                              hipStream_t stream) {
    const float* x      = (const float*)d_in[0];
    const int*   x_type = (const int*)d_in[1];
    const float* W      = (const float*)d_in[2];
    float* out          = (float*)d_out;

    // ws layout: meta (256 B) | row_ids (8*N ints = 1 MB) | Wt (4 MB bf16)
    char* ws = (char*)d_ws;
    size_t off_rids = 256;
    size_t off_wt   = off_rids + sizeof(int) * (size_t)N_TYPES * N_ROWS;
    int* meta    = (int*)ws;
    int* row_ids = (int*)(ws + off_rids);
    ushort* Wt   = (ushort*)(ws + off_wt);

    hipMemsetAsync(meta, 0, sizeof(int) * N_TYPES, stream);
    hipMemsetAsync(row_ids, 0xFF, sizeof(int) * (size_t)N_TYPES * N_ROWS, stream);
    k_fill<<<N_ROWS / 256, 256, 0, stream>>>(x_type, meta, row_ids);

    dim3 wgrid(N_TYPES, K_DIM / 64, OUT_DIM / 64);
    k_wt<<<wgrid, 256, 0, stream>>>(W, Wt);

    // row-tiles fastest: the second column pass over x comes a full pass
    // later -> L3-absorbed (r6/r12/r14 evidence: ~82-85 MB FETCH)
    dim3 ggrid(N_TYPES * TPB, OUT_DIM / BN);
    k_gemm14<<<ggrid, 512, 0, stream>>>(x, Wt, meta, row_ids, out);
}

// Round 16
// 68.938 us; speedup vs baseline: 1.0415x; 1.0415x over previous
//
#include <hip/hip_runtime.h>
#include <hip/hip_bf16.h>

#define N_ROWS 32768
#define K_DIM 512
#define OUT_DIM 512
#define N_TYPES 8
#define BM 64
#define BN 256
#define BK 32
#define NT (K_DIM / BK)     // 16 K-steps
#define TPB 512             // row-tiles per type (fixed segment: 512*64 = N)
#define ABUF 4096           // bytes per A buffer = 64 rows x 64 B   (CHECKED)
#define BBUF 16384          // bytes per B buffer = 256 cols x 64 B  (CHECKED)

typedef __attribute__((ext_vector_type(8))) short bf16x8;
typedef __attribute__((ext_vector_type(4))) float f32x4;

__device__ inline ushort f2bf(float f) {
    __hip_bfloat16 h = __float2bfloat16(f);
    return *reinterpret_cast<ushort*>(&h);
}

__device__ inline void gload_lds16(const void* g, void* l) {
    __builtin_amdgcn_global_load_lds(
        (const __attribute__((address_space(1))) void*)g,
        (__attribute__((address_space(3))) void*)l, 16, 0, 0);
}

// meta[0..7] = per-type cursors; final value after k_fill = per-type count.
// row_ids: fixed 1-MB layout, segment t at [t*N_ROWS, ...), rest stays -1.
__global__ void k_fill(const int* __restrict__ x_type, int* meta, int* __restrict__ row_ids) {
    __shared__ int lcnt[N_TYPES];
    __shared__ int lbase[N_TYPES];
    if (threadIdx.x < N_TYPES) lcnt[threadIdx.x] = 0;
    __syncthreads();
    int i = blockIdx.x * 256 + threadIdx.x;
    int t = x_type[i];
    int lpos = atomicAdd(&lcnt[t], 1);
    __syncthreads();
    if (threadIdx.x < N_TYPES)
        lbase[threadIdx.x] = (lcnt[threadIdx.x] > 0)
            ? atomicAdd(&meta[threadIdx.x], lcnt[threadIdx.x]) : 0;
    __syncthreads();
    row_ids[(size_t)t * N_ROWS + lbase[t] + lpos] = i;
}

// W[t][k][c] fp32 -> Wt[t][c][k] bf16   (64x64 tiles through LDS)
__global__ void k_wt(const float* __restrict__ W, ushort* __restrict__ Wt) {
    __shared__ float tile[64][65];
    int t = blockIdx.x, kb = blockIdx.y, cb = blockIdx.z;
    const float* src = W + (size_t)t * K_DIM * OUT_DIM + (size_t)kb * 64 * OUT_DIM + cb * 64;
    #pragma unroll
    for (int j = 0; j < 16; ++j) {
        int idx = threadIdx.x + j * 256;
        int r = idx >> 6, c = idx & 63;
        tile[r][c] = src[(size_t)r * OUT_DIM + c];
    }
    __syncthreads();
    ushort* dst = Wt + (size_t)t * OUT_DIM * K_DIM + (size_t)(cb * 64) * K_DIM + kb * 64;
    #pragma unroll
    for (int j = 0; j < 16; ++j) {
        int idx = threadIdx.x + j * 256;
        int cc = idx >> 6, kk = idx & 63;
        dst[(size_t)cc * K_DIM + kk] = f2bf(tile[kk][cc]);
    }
}

// r9 FIXED: 64x256 tile, 512 thr (8 waves of 32x64, acc[2][4]), BK=32
// DOUBLE-buffered 2-phase (stage t+1 before compute t, ONE barrier/step).
// LDS = 2x4K (A) + 2x16K (B) + rids = 40.5 KB -> 3 blocks/CU.
// ABUF=4096 (r9's crash was buf*8192 here), BBUF=16384 -- all audited.
// 64-B rows -> 4-slot XOR involution g^=(id&3): expect ~4-way read conflicts
// (~1.6x LDS cost, acceptable).  B via global_load_lds with involution folded
// into per-lane SOURCE (linear dest, rule #21); A reg-staged fp32->bf16.
__global__ __launch_bounds__(512, 4) void k_gemm15(
    const float* __restrict__ x, const ushort* __restrict__ Wt,
    const int* __restrict__ meta, const int* __restrict__ row_ids,
    float* __restrict__ out) {

    __shared__ ushort As[2 * BM * BK];   // 8192 B total
    __shared__ ushort Bs[2 * BN * BK];   // 32768 B total
    __shared__ int rids[BM];

    int b = blockIdx.x;              // 0..4095; row-tiles fastest
    int type = b >> 9;
    int r0 = (b & (TPB - 1)) * BM;
    if (r0 >= meta[type]) return;    // empty tile

    int tid = threadIdx.x;
    int wave = tid >> 6, lane = tid & 63;

    if (tid < BM) rids[tid] = row_ids[(size_t)type * N_ROWS + r0 + tid];
    __syncthreads();

    int c0 = blockIdx.y * BN;
    const ushort* Wtt = Wt + (size_t)type * OUT_DIM * K_DIM + (size_t)c0 * K_DIM;

    // ---- A staging role: 8 threads/row, 4 fp32 (16 B) -> 8 B bf16 each ----
    int sa_row  = tid >> 3;
    int sa_slot = tid & 7;           // 8-B slot within the 64-B row
    int sa_rid  = rids[sa_row];
    const float* sa_src = x + (size_t)max(sa_rid, 0) * K_DIM + sa_slot * 4;
    // swizzled write byte (16-B granule involution, 8-B sub-offset):
    int sa_byte = sa_row * 64 + (((sa_slot >> 1) ^ (sa_row & 3)) * 16) + (sa_slot & 1) * 8;

    // ---- B staging role: chunk = 16 cols x 64 B (1 KB); lane -> (col, g);
    //      source granule = g ^ (col&3)  (involution on SOURCE) ----
    int sb_col  = lane >> 2;                    // col within chunk (0..15)
    int sb_srcg = (lane & 3) ^ (sb_col & 3);    // source 16-B granule

    int wrb = (wave >> 2) * 32;      // wave row base (0/32)
    int wcb = (wave & 3) * 64;       // wave col base (0..192)
    int lrow = lane & 15;
    int g4   = lane >> 4;            // reader's 16-B k-granule (0..3)

    f32x4 acc[2][4] = {};

#define STAGE_B(buf, t)                                                         \
    _Pragma("unroll")                                                           \
    for (int j = 0; j < 2; ++j) {                                               \
        int chunk = wave * 2 + j;                                               \
        int col = chunk * 16 + sb_col;                                          \
        gload_lds16(Wtt + (size_t)col * K_DIM + (t) * BK + sb_srcg * 8,         \
                    (char*)Bs + (buf) * BBUF + chunk * 1024);                   \
    }

#define LOAD_X(t, v)                                                            \
    v = (sa_rid >= 0)                                                           \
        ? *reinterpret_cast<const float4*>(sa_src + (t) * BK)                   \
        : float4{0.f, 0.f, 0.f, 0.f};

#define WRITE_A(buf, v)                                                         \
    {                                                                           \
        ushort tmp[4] = { f2bf(v.x), f2bf(v.y), f2bf(v.z), f2bf(v.w) };         \
        *reinterpret_cast<uint2*>((char*)As + (buf) * ABUF + sa_byte) =         \
            *reinterpret_cast<const uint2*>(tmp);                               \
    }

#define COMPUTE(buf)                                                            \
    {                                                                           \
        bf16x8 af[2], bfr[4];                                                   \
        _Pragma("unroll")                                                       \
        for (int mi = 0; mi < 2; ++mi) {                                        \
            int row = wrb + mi * 16 + lrow;                                     \
            int byte = (buf) * ABUF + row * 64 + ((g4 ^ (row & 3)) * 16);       \
            af[mi] = *reinterpret_cast<const bf16x8*>((const char*)As + byte);  \
        }                                                                       \
        _Pragma("unroll")                                                       \
        for (int ni = 0; ni < 4; ++ni) {                                        \
            int col = wcb + ni * 16 + lrow;                                     \
            int byte = (buf) * BBUF + col * 64 + ((g4 ^ (col & 3)) * 16);       \
            bfr[ni] = *reinterpret_cast<const bf16x8*>((const char*)Bs + byte); \
        }                                                                       \
        _Pragma("unroll")                                                       \
        for (int mi = 0; mi < 2; ++mi)                                          \
            _Pragma("unroll")                                                   \
            for (int ni = 0; ni < 4; ++ni)                                      \
                acc[mi][ni] = __builtin_amdgcn_mfma_f32_16x16x32_bf16(          \
                    af[mi], bfr[ni], acc[mi][ni], 0, 0, 0);                     \
    }

    // ---- prologue: stage K-step 0 into buf 0 ----
    STAGE_B(0, 0)
    {
        float4 v;
        LOAD_X(0, v)
        WRITE_A(0, v)
    }
    __syncthreads();

    // ---- 2-phase main loop: ONE barrier per step ----
    #pragma unroll 2
    for (int t = 0; t < NT; ++t) {
        int cur = t & 1;
        float4 v;
        if (t < NT - 1) {
            STAGE_B(cur ^ 1, t + 1)      // into the other buffer, pre-issued
            LOAD_X(t + 1, v)
        }
        COMPUTE(cur)
        if (t < NT - 1) {
            WRITE_A(cur ^ 1, v)
            __syncthreads();             // drain lands after compute cover
        }
    }

    // epilogue: D row = (lane>>4)*4 + rr, col = lane&15
    int rgrp = g4 * 4;
    #pragma unroll
    for (int mi = 0; mi < 2; ++mi) {
        #pragma unroll
        for (int rr = 0; rr < 4; ++rr) {
            int lr = wrb + mi * 16 + rgrp + rr;
            int gr = rids[lr];
            if (gr >= 0) {
                float* dst = out + (size_t)gr * OUT_DIM + c0 + wcb;
                #pragma unroll
                for (int ni = 0; ni < 4; ++ni)
                    dst[ni * 16 + lrow] = acc[mi][ni][rr];
            }
        }
    }
}

extern "C" void kernel_launch(void* const* d_in, const int* in_sizes, int n_in,
                              void* d_out, int out_size, void* d_ws, size_t ws_size,
                              hipStream_t stream) {
    const float* x      = (const float*)d_in[0];
    const int*   x_type = (const int*)d_in[1];
    const float* W      = (const float*)d_in[2];
    float* out          = (float*)d_out;

    // ws layout: meta (256 B) | row_ids (8*N ints = 1 MB) | Wt (4 MB bf16)
    char* ws = (char*)d_ws;
    size_t off_rids = 256;
    size_t off_wt   = off_rids + sizeof(int) * (size_t)N_TYPES * N_ROWS;
    int* meta    = (int*)ws;
    int* row_ids = (int*)(ws + off_rids);
    ushort* Wt   = (ushort*)(ws + off_wt);

    hipMemsetAsync(meta, 0, sizeof(int) * N_TYPES, stream);
    hipMemsetAsync(row_ids, 0xFF, sizeof(int) * (size_t)N_TYPES * N_ROWS, stream);
    k_fill<<<N_ROWS / 256, 256, 0, stream>>>(x_type, meta, row_ids);

    dim3 wgrid(N_TYPES, K_DIM / 64, OUT_DIM / 64);
    k_wt<<<wgrid, 256, 0, stream>>>(W, Wt);

    // row-tiles fastest: second column pass over x comes a full pass later
    // -> L3-absorbed (r6/r12/r14 evidence: ~82-85 MB FETCH)
    dim3 ggrid(N_TYPES * TPB, OUT_DIM / BN);
    k_gemm15<<<ggrid, 512, 0, stream>>>(x, Wt, meta, row_ids, out);
}

// Round 17
// 62.802 us; speedup vs baseline: 1.1433x; 1.0977x over previous
//
#include <hip/hip_runtime.h>
#include <hip/hip_bf16.h>

#define N_ROWS 32768
#define K_DIM 512
#define OUT_DIM 512
#define N_TYPES 8
#define BM 64
#define BN 512              // FULL width: one column pass, x read exactly once
#define BK 64
#define TPB 512             // row-tiles per type (fixed segment: 512*64 = N)
#define DYN_LDS (8192 + 65536)   // A 64x128B + B 512x128B = 73728 B dynamic

typedef __attribute__((ext_vector_type(8))) short bf16x8;
typedef __attribute__((ext_vector_type(4))) float f32x4;

__device__ inline ushort f2bf(float f) {
    __hip_bfloat16 h = __float2bfloat16(f);
    return *reinterpret_cast<ushort*>(&h);
}

__device__ inline void gload_lds16(const void* g, void* l) {
    __builtin_amdgcn_global_load_lds(
        (const __attribute__((address_space(1))) void*)g,
        (__attribute__((address_space(3))) void*)l, 16, 0, 0);
}

// meta[0..7] = per-type cursors; final value after k_fill = per-type count.
// row_ids: fixed 1-MB layout, segment t at [t*N_ROWS, ...), rest stays -1.
__global__ void k_fill(const int* __restrict__ x_type, int* meta, int* __restrict__ row_ids) {
    __shared__ int lcnt[N_TYPES];
    __shared__ int lbase[N_TYPES];
    if (threadIdx.x < N_TYPES) lcnt[threadIdx.x] = 0;
    __syncthreads();
    int i = blockIdx.x * 256 + threadIdx.x;
    int t = x_type[i];
    int lpos = atomicAdd(&lcnt[t], 1);
    __syncthreads();
    if (threadIdx.x < N_TYPES)
        lbase[threadIdx.x] = (lcnt[threadIdx.x] > 0)
            ? atomicAdd(&meta[threadIdx.x], lcnt[threadIdx.x]) : 0;
    __syncthreads();
    row_ids[(size_t)t * N_ROWS + lbase[t] + lpos] = i;
}

// W[t][k][c] fp32 -> Wt[t][c][k] bf16   (64x64 tiles through LDS)
__global__ void k_wt(const float* __restrict__ W, ushort* __restrict__ Wt) {
    __shared__ float tile[64][65];
    int t = blockIdx.x, kb = blockIdx.y, cb = blockIdx.z;
    const float* src = W + (size_t)t * K_DIM * OUT_DIM + (size_t)kb * 64 * OUT_DIM + cb * 64;
    #pragma unroll
    for (int j = 0; j < 16; ++j) {
        int idx = threadIdx.x + j * 256;
        int r = idx >> 6, c = idx & 63;
        tile[r][c] = src[(size_t)r * OUT_DIM + c];
    }
    __syncthreads();
    ushort* dst = Wt + (size_t)t * OUT_DIM * K_DIM + (size_t)(cb * 64) * K_DIM + kb * 64;
    #pragma unroll
    for (int j = 0; j < 16; ++j) {
        int idx = threadIdx.x + j * 256;
        int cc = idx >> 6, kk = idx & 63;
        dst[(size_t)cc * K_DIM + kk] = f2bf(tile[kk][cc]);
    }
}

// 64x512 tile (ONE column pass), 512 thr, 8 waves each 64x64 out (acc[4][4],
// r3/r15-proven core: 32 MFMA + 16 ds_read_b128 per wave per barrier-pair —
// 2x r14's compute per event at HALF the chip-wide event count).
// A: r14's exact thin stage (8 thr/row, 8 fp32->bf16, swizzled ds_write).
// B: r14's exact involution global_load_lds mapping, 8 chunks/wave (64 KB/step).
// Dynamic LDS 72 KB -> 2 blocks/CU; ~520 active blocks ~= 2.03/CU balanced.
__global__ __launch_bounds__(512, 4) void k_gemm16(
    const float* __restrict__ x, const ushort* __restrict__ Wt,
    const int* __restrict__ meta, const int* __restrict__ row_ids,
    float* __restrict__ out) {

    extern __shared__ char smem[];       // [0,8192) = As, [8192,73728) = Bs
    __shared__ int rids[BM];

    int b = blockIdx.x;                  // 0..4095; row-tiles fastest
    int type = b >> 9;
    int r0 = (b & (TPB - 1)) * BM;
    if (r0 >= meta[type]) return;        // empty tile

    int tid = threadIdx.x;
    int wave = tid >> 6, lane = tid & 63;

    if (tid < BM) rids[tid] = row_ids[(size_t)type * N_ROWS + r0 + tid];
    __syncthreads();

    const ushort* Wtt = Wt + (size_t)type * OUT_DIM * K_DIM;

    // ---- A staging role: 8 threads/row, 8 elems (32 B fp32) each ----
    int sa_row  = tid >> 3;
    int sa_slot = tid & 7;               // 16-B bf16 granule within 128-B row
    int sa_rid  = rids[sa_row];
    const float* sa_src = x + (size_t)max(sa_rid, 0) * K_DIM + sa_slot * 8;
    int sa_byte = (sa_row * 128 + sa_slot * 16) ^ ((sa_row & 7) << 4);

    // ---- B staging role: chunk = 8 cols x 128 B (1 KB); lane -> (col,pos);
    //      source granule = pos ^ (col&7)  (involution on SOURCE, rule #21) ----
    int sb_colgrp = lane >> 3;                               // 0..7
    int sb_koff   = (((lane & 7) * 16) ^ (sb_colgrp << 4)) >> 1;  // elems

    int wcb = wave * 64;                 // wave col base (0..448); rows 0..63
    int lrow = lane & 15;
    int lkb16 = (lane >> 4) * 16;        // 16-B k-fragment offset

    f32x4 acc[4][4] = {};

    #pragma unroll 1
    for (int kk = 0; kk < K_DIM; kk += BK) {
        // ---- stage B: 8 chunks/wave, 64 chunks = 512 cols (64 KB) ----
        #pragma unroll
        for (int j = 0; j < 8; ++j) {
            int chunk = wave * 8 + j;
            int col = chunk * 8 + sb_colgrp;
            gload_lds16(Wtt + (size_t)col * K_DIM + kk + sb_koff,
                        smem + 8192 + chunk * 1024);
        }
        // ---- stage A: 8 fp32 -> 8 bf16, 1 swizzled ds_write_b128 ----
        {
            ushort tmp[8] = {0, 0, 0, 0, 0, 0, 0, 0};
            if (sa_rid >= 0) {
                float4 v0 = *reinterpret_cast<const float4*>(sa_src + kk);
                float4 v1 = *reinterpret_cast<const float4*>(sa_src + kk + 4);
                tmp[0] = f2bf(v0.x); tmp[1] = f2bf(v0.y); tmp[2] = f2bf(v0.z); tmp[3] = f2bf(v0.w);
                tmp[4] = f2bf(v1.x); tmp[5] = f2bf(v1.y); tmp[6] = f2bf(v1.z); tmp[7] = f2bf(v1.w);
            }
            *reinterpret_cast<uint4*>(smem + sa_byte) = *reinterpret_cast<const uint4*>(tmp);
        }
        __syncthreads();

        // ---- compute: 2 k-halves x 16 MFMA (32 MFMA, 16 ds_read_b128) ----
        #pragma unroll
        for (int s = 0; s < 2; ++s) {
            bf16x8 af[4], bfr[4];
            #pragma unroll
            for (int mi = 0; mi < 4; ++mi) {
                int row = mi * 16 + lrow;
                int byte = (row * 128 + s * 64 + lkb16) ^ ((row & 7) << 4);
                af[mi] = *reinterpret_cast<const bf16x8*>(smem + byte);
            }
            #pragma unroll
            for (int ni = 0; ni < 4; ++ni) {
                int col = wcb + ni * 16 + lrow;
                int byte = (col * 128 + s * 64 + lkb16) ^ ((col & 7) << 4);
                bfr[ni] = *reinterpret_cast<const bf16x8*>(smem + 8192 + byte);
            }
            #pragma unroll
            for (int mi = 0; mi < 4; ++mi)
                #pragma unroll
                for (int ni = 0; ni < 4; ++ni)
                    acc[mi][ni] = __builtin_amdgcn_mfma_f32_16x16x32_bf16(
                        af[mi], bfr[ni], acc[mi][ni], 0, 0, 0);
        }
        __syncthreads();
    }

    // epilogue: D row = (lane>>4)*4 + rr, col = lane&15
    int rgrp = (lane >> 4) * 4;
    #pragma unroll
    for (int mi = 0; mi < 4; ++mi) {
        #pragma unroll
        for (int rr = 0; rr < 4; ++rr) {
            int lr = mi * 16 + rgrp + rr;
            int gr = rids[lr];
            if (gr >= 0) {
                float* dst = out + (size_t)gr * OUT_DIM + wcb;
                #pragma unroll
                for (int ni = 0; ni < 4; ++ni)
                    dst[ni * 16 + lrow] = acc[mi][ni][rr];
            }
        }
    }
}

extern "C" void kernel_launch(void* const* d_in, const int* in_sizes, int n_in,
                              void* d_out, int out_size, void* d_ws, size_t ws_size,
                              hipStream_t stream) {
    const float* x      = (const float*)d_in[0];
    const int*   x_type = (const int*)d_in[1];
    const float* W      = (const float*)d_in[2];
    float* out          = (float*)d_out;

    // ws layout: meta (256 B) | row_ids (8*N ints = 1 MB) | Wt (4 MB bf16)
    char* ws = (char*)d_ws;
    size_t off_rids = 256;
    size_t off_wt   = off_rids + sizeof(int) * (size_t)N_TYPES * N_ROWS;
    int* meta    = (int*)ws;
    int* row_ids = (int*)(ws + off_rids);
    ushort* Wt   = (ushort*)(ws + off_wt);

    // allow 72 KB dynamic LDS (host-side attribute; not a stream op)
    hipFuncSetAttribute((const void*)k_gemm16,
                        hipFuncAttributeMaxDynamicSharedMemorySize, DYN_LDS);

    hipMemsetAsync(meta, 0, sizeof(int) * N_TYPES, stream);
    hipMemsetAsync(row_ids, 0xFF, sizeof(int) * (size_t)N_TYPES * N_ROWS, stream);
    k_fill<<<N_ROWS / 256, 256, 0, stream>>>(x_type, meta, row_ids);

    dim3 wgrid(N_TYPES, K_DIM / 64, OUT_DIM / 64);
    k_wt<<<wgrid, 256, 0, stream>>>(W, Wt);

    // single column pass: x read exactly once from HBM
    k_gemm16<<<N_TYPES * TPB, 512, DYN_LDS, stream>>>(x, Wt, meta, row_ids, out);
}